// Round 4
// baseline (276.030 us; speedup 1.0000x reference)
//
#include <hip/hip_runtime.h>

#define BOUND 1e-6f
#define HALF_PI 1.57079632679489662f

// DPP helper: masked/out-of-range lanes receive `oldv` (we pass 1.0f, the
// multiplicative identity). ctrl/row_mask must be literal constants.
#define UPD_DPP(oldv, srcv, ctrl, rmask)                                        \
  __int_as_float(__builtin_amdgcn_update_dpp(                                   \
      __float_as_int(oldv), __float_as_int(srcv), (ctrl), (rmask), 0xF, false))

// Inclusive multiplicative scan across 64 lanes, pure VALU (validated R2/R3).
__device__ __forceinline__ float wave_incl_prod(float x) {
    x *= UPD_DPP(1.0f, x, 0x111, 0xF);  // row_shr:1
    x *= UPD_DPP(1.0f, x, 0x112, 0xF);  // row_shr:2
    x *= UPD_DPP(1.0f, x, 0x114, 0xF);  // row_shr:4
    x *= UPD_DPP(1.0f, x, 0x118, 0xF);  // row_shr:8
    x *= UPD_DPP(1.0f, x, 0x142, 0xA);  // row_bcast:15 -> rows 1,3
    x *= UPD_DPP(1.0f, x, 0x143, 0xC);  // row_bcast:31 -> rows 2,3
    return x;
}

// CHUNKED assignment: wave w owns rows [w*rpw, (w+1)*rpw) -- a contiguous
// 64KB read / 65.8KB write region -- instead of grid-striding. This (a) makes
// output row-boundary cachelines merge within ONE wave's L2, (b) cuts the
// number of concurrently-advancing DRAM address streams 2x and makes each
// 64x longer. Grid = 2048 blocks x 4 waves = 8192 waves = exactly resident.
// Depth-2 rotating prefetch keeps 2KB/wave of reads in flight.
// out[j]   = radius * prod_{i<j}(sin(a_i)+B) * (cos(a_j)+B),  j < 256
// out[256] = radius * prod_{i<256}(sin(a_i)+B)
__global__ __launch_bounds__(256) void spherize_kernel(
    const float* __restrict__ x,
    const float* __restrict__ p_phiL,
    const float* __restrict__ p_radius,
    const float* __restrict__ p_scaling,
    float* __restrict__ out,
    int n_rows, int rows_per_wave)
{
    const float phi_L   = p_phiL[0];
    const float radius  = p_radius[0];
    const float scaling = p_scaling[0];
    const float amp     = HALF_PI - phi_L;

    const int lane          = threadIdx.x & 63;
    const int wave_in_block = threadIdx.x >> 6;
    const int wave_id       = blockIdx.x * (blockDim.x >> 6) + wave_in_block;

    const int r0   = wave_id * rows_per_wave;
    if (r0 >= n_rows) return;
    int rend = r0 + rows_per_wave;
    if (rend > n_rows) rend = n_rows;
    const int nr = rend - r0;

    const float* xb = x   + (size_t)r0 * 256 + lane * 4;
    float*       ob = out + (size_t)r0 * 257 + lane * 4;

    // depth-2 prefetch pipeline over consecutive rows
    float4 buf0 = *reinterpret_cast<const float4*>(xb);
    float4 buf1 = (nr > 1) ? *reinterpret_cast<const float4*>(xb + 256)
                           : make_float4(0.f, 0.f, 0.f, 0.f);
    const float* xp2 = xb + 512;

    #pragma unroll 2
    for (int i = 0; i < nr; ++i) {
        float4 cur = buf0;
        buf0 = buf1;
        if (i + 2 < nr) {
            buf1 = *reinterpret_cast<const float4*>(xp2);
        }
        xp2 += 256;

        const float* xv = &cur.x;
        float s[4], c[4];
        #pragma unroll
        for (int k = 0; k < 4; ++k) {
            float e  = __expf(-scaling * xv[k]);
            float sg = __builtin_amdgcn_rcpf(1.0f + e);
            float a  = fmaf(amp, sg, phi_L);   // a in [phi_L, pi/2)
            s[k] = __sinf(a) + BOUND;
            c[k] = __cosf(a) + BOUND;
        }

        float q1 = s[0];
        float q2 = q1 * s[1];
        float q3 = q2 * s[2];
        float t  = q3 * s[3];
        float scan = wave_incl_prod(t);          // inclusive over lanes
        float excl = __shfl_up(scan, 1, 64);     // product of lanes < me
        float base = radius * ((lane == 0) ? 1.0f : excl);

        ob[0] = base * c[0];
        ob[1] = base * q1 * c[1];
        ob[2] = base * q2 * c[2];
        ob[3] = base * q3 * c[3];
        if (lane == 63)
            ob[4] = radius * scan;               // col 256: full product
        ob += 257;
    }
}

extern "C" void kernel_launch(void* const* d_in, const int* in_sizes, int n_in,
                              void* d_out, int out_size, void* d_ws, size_t ws_size,
                              hipStream_t stream) {
    // inputs: 0=x [N,256], 1=W_theta, 2=W_phi, 3=b_phi, 4=phi_L, 5=radius, 6=scaling
    const float* x         = (const float*)d_in[0];
    const float* p_phiL    = (const float*)d_in[4];
    const float* p_radius  = (const float*)d_in[5];
    const float* p_scaling = (const float*)d_in[6];
    float* out = (float*)d_out;

    const int n_rows = in_sizes[0] / 256;
    const int blocks = 2048;                 // x4 waves = 8192 = exactly resident
    const int total_waves = blocks * 4;
    const int rows_per_wave = (n_rows + total_waves - 1) / total_waves;  // 64

    spherize_kernel<<<blocks, 256, 0, stream>>>(x, p_phiL, p_radius, p_scaling,
                                                out, n_rows, rows_per_wave);
}

// Round 5
// 208.767 us; speedup vs baseline: 1.3222x; 1.3222x over previous
//
#include <hip/hip_runtime.h>

#define BOUND 1e-6f
#define HALF_PI 1.57079632679489662f

// DPP helper: masked/out-of-range lanes receive `oldv` (1.0 = mult identity).
#define UPD_DPP(oldv, srcv, ctrl, rmask)                                        \
  __int_as_float(__builtin_amdgcn_update_dpp(                                   \
      __float_as_int(oldv), __float_as_int(srcv), (ctrl), (rmask), 0xF, false))

// Inclusive multiplicative scan across 64 lanes, pure VALU (validated R2-R4).
__device__ __forceinline__ float wave_incl_prod(float x) {
    x *= UPD_DPP(1.0f, x, 0x111, 0xF);  // row_shr:1
    x *= UPD_DPP(1.0f, x, 0x112, 0xF);  // row_shr:2
    x *= UPD_DPP(1.0f, x, 0x114, 0xF);  // row_shr:4
    x *= UPD_DPP(1.0f, x, 0x118, 0xF);  // row_shr:8
    x *= UPD_DPP(1.0f, x, 0x142, 0xA);  // row_bcast:15 -> rows 1,3
    x *= UPD_DPP(1.0f, x, 0x143, 0xC);  // row_bcast:31 -> rows 2,3
    return x;
}

// Block = 512 threads (8 waves) owns 32 consecutive rows. Compute into LDS
// (32 x 257 f32 = 32896 B; 32896 % 128 == 0 so each block's output region is
// cacheline-ALIGNED and consists of FULL lines only). Cooperative aligned
// float4 store of the whole region -> no partial-line writes -> no L2
// write-allocate/RMW fetch of the output (the hypothesized 2x write cost).
// out[j]   = radius * prod_{i<j}(sin(a_i)+B) * (cos(a_j)+B),  j < 256
// out[256] = radius * prod_{i<256}(sin(a_i)+B)
__global__ __launch_bounds__(512) void spherize_kernel(
    const float* __restrict__ x,
    const float* __restrict__ p_phiL,
    const float* __restrict__ p_radius,
    const float* __restrict__ p_scaling,
    float* __restrict__ out,
    int n_rows)
{
    __shared__ float lds[32 * 257];   // 32896 B

    const float phi_L   = p_phiL[0];
    const float radius  = p_radius[0];
    const float scaling = p_scaling[0];
    const float amp     = HALF_PI - phi_L;

    const int tid  = threadIdx.x;
    const int lane = tid & 63;
    const int wave = tid >> 6;              // 0..7
    const int row0 = blockIdx.x * 32;       // block's first row
    const int wrow = row0 + wave * 4;       // this wave's first row

    const int nr_blk = min(32, n_rows - row0);        // rows in this block
    const int nr_w   = min(4, max(0, n_rows - wrow)); // rows for this wave

    // ---- load this wave's rows up front (up to 4 KB in flight) ----
    float4 xv[4];
    const float* xb = x + (size_t)wrow * 256 + lane * 4;
    #pragma unroll
    for (int i = 0; i < 4; ++i)
        if (i < nr_w) xv[i] = *reinterpret_cast<const float4*>(xb + i * 256);

    // ---- compute rows into LDS (validated math) ----
    #pragma unroll
    for (int i = 0; i < 4; ++i) {
        if (i >= nr_w) break;
        const float* xp = &xv[i].x;
        float s[4], c[4];
        #pragma unroll
        for (int k = 0; k < 4; ++k) {
            float e  = __expf(-scaling * xp[k]);
            float sg = __builtin_amdgcn_rcpf(1.0f + e);
            float a  = fmaf(amp, sg, phi_L);   // a in [phi_L, pi/2)
            s[k] = __sinf(a) + BOUND;
            c[k] = __cosf(a) + BOUND;
        }
        float q1 = s[0];
        float q2 = q1 * s[1];
        float q3 = q2 * s[2];
        float t  = q3 * s[3];
        float scan = wave_incl_prod(t);          // inclusive over lanes
        float excl = __shfl_up(scan, 1, 64);     // product of lanes < me
        float base = radius * ((lane == 0) ? 1.0f : excl);

        float* lrow = lds + (wave * 4 + i) * 257 + lane * 4;
        lrow[0] = base * c[0];
        lrow[1] = base * q1 * c[1];
        lrow[2] = base * q2 * c[2];
        lrow[3] = base * q3 * c[3];
        if (lane == 63)
            lrow[4] = radius * scan;             // col 256: full product
    }
    __syncthreads();

    // ---- cooperative aligned full-line store of the block's region ----
    float* obase = out + (size_t)row0 * 257;
    if (nr_blk == 32) {
        // 32*257 = 8224 dwords = 2056 float4s, region 128B-aligned
        const float4* l4 = reinterpret_cast<const float4*>(lds);
        float4*       o4 = reinterpret_cast<float4*>(obase);
        o4[tid]        = l4[tid];
        o4[tid + 512]  = l4[tid + 512];
        o4[tid + 1024] = l4[tid + 1024];
        o4[tid + 1536] = l4[tid + 1536];
        if (tid < 8) o4[tid + 2048] = l4[tid + 2048];
    } else {
        // tail block (not hit for N=524288): safe dword cooperative store
        const int nd = nr_blk * 257;
        for (int i = tid; i < nd; i += 512) obase[i] = lds[i];
    }
}

extern "C" void kernel_launch(void* const* d_in, const int* in_sizes, int n_in,
                              void* d_out, int out_size, void* d_ws, size_t ws_size,
                              hipStream_t stream) {
    // inputs: 0=x [N,256], 1=W_theta, 2=W_phi, 3=b_phi, 4=phi_L, 5=radius, 6=scaling
    const float* x         = (const float*)d_in[0];
    const float* p_phiL    = (const float*)d_in[4];
    const float* p_radius  = (const float*)d_in[5];
    const float* p_scaling = (const float*)d_in[6];
    float* out = (float*)d_out;

    const int n_rows = in_sizes[0] / 256;
    const int blocks = (n_rows + 31) / 32;   // 16384 for N=524288

    spherize_kernel<<<blocks, 512, 0, stream>>>(x, p_phiL, p_radius, p_scaling,
                                                out, n_rows);
}